// Round 10
// baseline (311.749 us; speedup 1.0000x reference)
//
#include <hip/hip_runtime.h>
#include <hip/hip_bf16.h>

#define NTOK 9216   // H*W
#define CCH  256    // C
#define DQK  32     // CQ
#define BJ   128    // j-columns per attention block
#define BI   64     // i-rows per iteration
#define SSEG 4      // i-split factor (segments of 2304 rows)
#define SI   88     // Pl row stride (shorts): 176B rows, 16B aligned; 44 dw = 12 mod 32 -> ~2-way banks

typedef __attribute__((ext_vector_type(8))) short short8;
typedef __attribute__((ext_vector_type(4))) float f32x4;

__device__ __forceinline__ unsigned short f2bf(float x) {
    union { float f; unsigned int u; } v; v.f = x;
    return (unsigned short)((v.u + 0x7FFF + ((v.u >> 16) & 1)) >> 16); // RNE
}

#if __has_builtin(__builtin_amdgcn_cvt_pk_bf16_f32)
__device__ __forceinline__ unsigned int pack2bf(float a, float b) {
    auto p = __builtin_amdgcn_cvt_pk_bf16_f32(a, b);   // 1 VALU op (gfx950 HW cvt)
    union { decltype(p) v; unsigned int u; } cv; cv.v = p; return cv.u;
}
#else
__device__ __forceinline__ unsigned int pack2bf(float a, float b) {
    return (unsigned)f2bf(a) | ((unsigned)f2bf(b) << 16);
}
#endif

// scores arrive pre-scaled by log2(e)  ->  P = 2^sc = e^s, raw v_exp_f32
#if __has_builtin(__builtin_amdgcn_exp2f)
#define EXP2(x) __builtin_amdgcn_exp2f(x)
#else
#define EXP2(x) __expf((x) * 0.69314718055994531f)
#endif

// ---------------- Kernel 0: w -> bf16 ----------------
__global__ __launch_bounds__(256) void wcvt_kernel(
    const float* __restrict__ w, unsigned short* __restrict__ wbf)
{
    const int i = (blockIdx.x * 256 + threadIdx.x) * 4;  // 320*256 = 81920 elems
    f32x4 v = *(const f32x4*)(w + i);
    *(unsigned int*)(wbf + i)     = pack2bf(v[0], v[1]);
    *(unsigned int*)(wbf + i + 2) = pack2bf(v[2], v[3]);
}

// ---------------- Kernel 1: QKV projection via MFMA (validated R8/R9, ~40 us) ----------------
// qkv[o][n] = sum_c w[o][c]*x[b][c][n].  Block = 16-n-tile; wave wv owns
// o in [80wv, 80wv+80) as 5 o-tiles of 16.  A = wbf rows (contiguous short8),
// B = x columns built in-register from 8 coalesced dword loads + cvt.
// qT is pre-scaled by log2(e) so attn can use raw v_exp_f32.
__global__ __launch_bounds__(256) void qkv_kernel(
    const float* __restrict__ x, const unsigned short* __restrict__ wbf,
    unsigned short* __restrict__ qT, unsigned short* __restrict__ kT,
    unsigned short* __restrict__ vcn)
{
    const int id   = blockIdx.x;      // 1152 = 576 n-tiles x 2 b
    const int b    = id & 1;
    const int n0   = (id >> 1) * 16;
    const int t    = threadIdx.x;
    const int wv   = t >> 6;
    const int lane = t & 63;
    const int l15  = lane & 15;
    const int qd   = lane >> 4;

    const float* xb = x + (size_t)b * CCH * NTOK + n0 + l15;

    f32x4 acc[5];
#pragma unroll
    for (int tt = 0; tt < 5; ++tt) acc[tt] = (f32x4){0.f, 0.f, 0.f, 0.f};

    const unsigned short* wrow = wbf + (size_t)(80 * wv + l15) * CCH + qd * 8;

#pragma unroll
    for (int kk = 0; kk < 8; ++kk) {
        // B-frag: B[k=c=32kk+8qd+e][n=n0+l15]; 8 coalesced dword loads
        float xe[8];
#pragma unroll
        for (int e = 0; e < 8; ++e)
            xe[e] = xb[(size_t)(32 * kk + 8 * qd + e) * NTOK];
        short8 bfr;
#pragma unroll
        for (int e = 0; e < 8; ++e)
            bfr[e] = (short)f2bf(xe[e]);
        // A-frags: A[m=o-local=l15][k=32kk+8qd+e] from wbf row o=80wv+16tt+l15
#pragma unroll
        for (int tt = 0; tt < 5; ++tt) {
            short8 afr = *(const short8*)(wrow + (size_t)(16 * tt) * CCH + 32 * kk);
            acc[tt] = __builtin_amdgcn_mfma_f32_16x16x32_bf16(afr, bfr, acc[tt], 0, 0, 0);
        }
    }

    // store: D[row = o_local = 4qd+r][col = n = n0+l15]; branch uniform per (wv,tt)
    const int n = n0 + l15;
    const float L2E = 1.44269504088896f;
#pragma unroll
    for (int tt = 0; tt < 5; ++tt) {
        const int o0l = 80 * wv + 16 * tt + 4 * qd;   // + r, r=0..3
        if (o0l < 32) {
            unsigned short* d = qT + ((size_t)b * NTOK + n) * DQK + o0l;
            *(unsigned int*)d       = pack2bf(acc[tt][0] * L2E, acc[tt][1] * L2E);
            *(unsigned int*)(d + 2) = pack2bf(acc[tt][2] * L2E, acc[tt][3] * L2E);
        } else if (o0l < 64) {
            unsigned short* d = kT + ((size_t)b * NTOK + n) * DQK + (o0l - 32);
            *(unsigned int*)d       = pack2bf(acc[tt][0], acc[tt][1]);
            *(unsigned int*)(d + 2) = pack2bf(acc[tt][2], acc[tt][3]);
        } else {
            unsigned short* d = vcn + ((size_t)b * CCH + (o0l - 64)) * NTOK + n;
            d[0] = f2bf(acc[tt][0]);
            d[(size_t)NTOK] = f2bf(acc[tt][1]);
            d[(size_t)2 * NTOK] = f2bf(acc[tt][2]);
            d[(size_t)3 * NTOK] = f2bf(acc[tt][3]);
        }
    }
}

// ---------------- Kernel 2: split-i flash attention partials ----------------
// 1152 blocks = 8 XCD-combos (seg x c-half) x 144 (j-block x b); V chunk per
// XCD is L2-resident (R7/R9: FETCH 13.7 MB). Double-buffered Pl -> 1 barrier
// per iter.  KEEP __launch_bounds__(256,3): (256,4) forced VGPR 84->64 and
// spilled ~2 GB scratch traffic in R8 (FETCH 690 MB, 2.9x slower).
__global__ __launch_bounds__(256, 3) void attn_partial_kernel(
    const unsigned short* __restrict__ qT, const unsigned short* __restrict__ kT,
    const unsigned short* __restrict__ vcn,
    float* __restrict__ Opart, float* __restrict__ lpart)
{
    __shared__ __align__(16) unsigned short Pl[2][BJ * SI]; // 45056 B
    __shared__ float lred2[2 * BJ];                         // 1024 B

    const int id  = blockIdx.x;
    const int xcd = id & 7;
    const int s   = xcd >> 1;          // i-segment 0..3
    const int cb  = xcd & 1;           // c-half 0..1
    const int r   = id >> 3;           // 0..143
    const int jb  = r % 72;
    const int b   = r / 72;

    const int t    = threadIdx.x;
    const int wv   = t >> 6;
    const int lane = t & 63;
    const int l15  = lane & 15;
    const int qd   = lane >> 4;
    const int jh   = wv >> 1;          // j-half within block
    const int u    = wv & 1;           // QK: i-subtile bit; PV: c-quarter bit
    const int j0   = jb * BJ;
    const int c0   = cb * 128;
    const int iBeg = s * (NTOK / SSEG);
    const int iEnd = iBeg + (NTOK / SSEG);

    // resident k B-frags: B[k=d=qd*8+e][n=j=64jh+16jt+l15]
    short8 kf[4];
#pragma unroll
    for (int jt = 0; jt < 4; ++jt)
        kf[jt] = *(const short8*)(kT +
            ((size_t)b * NTOK + j0 + 64 * jh + 16 * jt + l15) * DQK + qd * 8);

    f32x4 acc[4][4]; // O[j = j0+64jh+16mt+4qd+r][c = c0+64u+16ct+l15]
#pragma unroll
    for (int mt = 0; mt < 4; ++mt)
#pragma unroll
        for (int ct = 0; ct < 4; ++ct)
            acc[mt][ct] = (f32x4){0.f, 0.f, 0.f, 0.f};
    float lw[4] = {0.f, 0.f, 0.f, 0.f}; // partial l, col j = 64jh+16jt+l15

    const unsigned short* qrow =
        qT + (size_t)b * NTOK * DQK + (size_t)(16 * u + l15) * DQK + qd * 8;
    const unsigned short* vrow =
        vcn + ((size_t)b * CCH + c0 + 64 * u + l15) * NTOK + qd * 8;

    int pb = 0;
    for (int i0 = iBeg; i0 < iEnd; i0 += BI, pb ^= 1) {
        // A-frags of q rows: af[it] -> i = i0 + 32it + 16u + l15
        short8 af[2];
#pragma unroll
        for (int it = 0; it < 2; ++it)
            af[it] = *(const short8*)(qrow + (size_t)(i0 + 32 * it) * DQK);
        // V B-frags: B[k=i_loc=32kc+qd*8+e][n=c=c0+64u+16ct+l15]
        short8 vf[2][4];
#pragma unroll
        for (int kc = 0; kc < 2; ++kc)
#pragma unroll
            for (int ct = 0; ct < 4; ++ct)
                vf[kc][ct] = *(const short8*)(vrow + (size_t)(16 * ct) * NTOK + i0 + 32 * kc);

        // QK: sc = S[i = i0+32it+16u+4qd+rr][j = j0+64jh+16jt+l15] * log2e
        unsigned short* Plc = Pl[pb];
#pragma unroll
        for (int it = 0; it < 2; ++it) {
#pragma unroll
            for (int jt = 0; jt < 4; ++jt) {
                f32x4 sc = __builtin_amdgcn_mfma_f32_16x16x32_bf16(
                    af[it], kf[jt], (f32x4){0.f, 0.f, 0.f, 0.f}, 0, 0, 0);
                float p0 = EXP2(sc[0]);
                float p1 = EXP2(sc[1]);
                float p2 = EXP2(sc[2]);
                float p3 = EXP2(sc[3]);
                lw[jt] += (p0 + p1) + (p2 + p3);
                // Pl[j_loc][i_loc], i_loc = 32it+16u+4qd+{0..3} (dword aligned)
                int base = (64 * jh + 16 * jt + l15) * SI + 32 * it + 16 * u + 4 * qd;
                *(unsigned int*)(Plc + base)     = pack2bf(p0, p1);
                *(unsigned int*)(Plc + base + 2) = pack2bf(p2, p3);
            }
        }
        __syncthreads(); // single barrier: Pl[pb] visible; prev buffer is safe to
                         // rewrite only after NEXT barrier -> dbuf correct

        // PV: A = Pl rows (m=l15 -> j=64jh+16mt+l15, k=32kc+qd*8+e), B = vf
#pragma unroll
        for (int kc = 0; kc < 2; ++kc) {
            short8 pa[4];
#pragma unroll
            for (int mt = 0; mt < 4; ++mt)
                pa[mt] = *(const short8*)(Plc + (64 * jh + 16 * mt + l15) * SI + 32 * kc + qd * 8);
#pragma unroll
            for (int mt = 0; mt < 4; ++mt)
#pragma unroll
                for (int ct = 0; ct < 4; ++ct)
                    acc[mt][ct] = __builtin_amdgcn_mfma_f32_16x16x32_bf16(
                        pa[mt], vf[kc][ct], acc[mt][ct], 0, 0, 0);
        }
    }

    // l partial: sum over qd (this wave covered i-subsets 32it+16u+[0,16))
#pragma unroll
    for (int jt = 0; jt < 4; ++jt) {
        lw[jt] += __shfl_xor(lw[jt], 16);
        lw[jt] += __shfl_xor(lw[jt], 32);
    }
    if (qd == 0) {
#pragma unroll
        for (int jt = 0; jt < 4; ++jt)
            lred2[u * BJ + 64 * jh + 16 * jt + l15] = lw[jt];
    }
    __syncthreads();
    if (cb == 0 && t < BJ)   // c-half 1 computes identical l; write once
        lpart[(size_t)(s * 2 + b) * NTOK + j0 + t] = lred2[t] + lred2[BJ + t];

    // store raw partial O (plain, disjoint, coalesced f32x4 along j)
#pragma unroll
    for (int mt = 0; mt < 4; ++mt)
#pragma unroll
        for (int ct = 0; ct < 4; ++ct) {
            int c = c0 + 64 * u + 16 * ct + l15;
            int j = j0 + 64 * jh + 16 * mt + 4 * qd;
            float* p = Opart + ((size_t)(s * 2 + b) * CCH + c) * NTOK + j;
            *(f32x4*)p = acc[mt][ct];
        }
}

// ---------------- Kernel 3: reduce partials + normalize + residual ----------------
__global__ __launch_bounds__(256) void reduce_kernel(
    const float* __restrict__ Opart, const float* __restrict__ lpart,
    const float* __restrict__ x, const float* __restrict__ gamma,
    float* __restrict__ out)
{
    const size_t flat = ((size_t)blockIdx.x * 256 + threadIdx.x) * 4;
    const int j = (int)(flat % NTOK);
    const int b = (int)(flat / ((size_t)CCH * NTOK));
    const size_t inb = flat - (size_t)b * CCH * NTOK;  // c*NTOK + j

    f32x4 o = {0.f, 0.f, 0.f, 0.f};
    f32x4 l = {0.f, 0.f, 0.f, 0.f};
#pragma unroll
    for (int s = 0; s < SSEG; ++s) {
        const size_t plane = (size_t)(s * 2 + b) * CCH * NTOK;
        f32x4 ov = *(const f32x4*)(Opart + plane + inb);
        f32x4 lv = *(const f32x4*)(lpart + (size_t)(s * 2 + b) * NTOK + j);
        o[0] += ov[0]; o[1] += ov[1]; o[2] += ov[2]; o[3] += ov[3];
        l[0] += lv[0]; l[1] += lv[1]; l[2] += lv[2]; l[3] += lv[3];
    }
    const float g = gamma[0];
    f32x4 xv = *(const f32x4*)(x + flat);
    f32x4 rr;
    rr[0] = g * o[0] / l[0] + xv[0];
    rr[1] = g * o[1] / l[1] + xv[1];
    rr[2] = g * o[2] / l[2] + xv[2];
    rr[3] = g * o[3] / l[3] + xv[3];
    *(f32x4*)(out + flat) = rr;
}

extern "C" void kernel_launch(void* const* d_in, const int* in_sizes, int n_in,
                              void* d_out, int out_size, void* d_ws, size_t ws_size,
                              hipStream_t stream) {
    const float* x     = (const float*)d_in[0];
    const float* w     = (const float*)d_in[1];
    const float* gamma = (const float*)d_in[2];
    float* out = (float*)d_out;

    unsigned short* qT  = (unsigned short*)d_ws;          // 1.18 MB
    unsigned short* kT  = qT + (size_t)2 * NTOK * DQK;    // 1.18 MB
    unsigned short* vcn = kT + (size_t)2 * NTOK * DQK;    // 9.44 MB
    float* Opart = (float*)(vcn + (size_t)2 * CCH * NTOK); // 75.5 MB
    float* lpart = Opart + (size_t)SSEG * 2 * CCH * NTOK;  // 295 KB
    unsigned short* wbf = (unsigned short*)(lpart + (size_t)SSEG * 2 * NTOK); // 164 KB

    wcvt_kernel<<<80, 256, 0, stream>>>(w, wbf);

    qkv_kernel<<<1152, 256, 0, stream>>>(x, wbf, qT, kT, vcn);

    attn_partial_kernel<<<1152, 256, 0, stream>>>(qT, kT, vcn, Opart, lpart);

    reduce_kernel<<<(unsigned)((size_t)2 * CCH * NTOK / 4 / 256), 256, 0, stream>>>(
        Opart, lpart, x, gamma, out);
}

// Round 11
// 301.336 us; speedup vs baseline: 1.0346x; 1.0346x over previous
//
#include <hip/hip_runtime.h>
#include <hip/hip_bf16.h>

#define NTOK 9216   // H*W
#define CCH  256    // C
#define DQK  32     // CQ
#define BJ   128    // j-columns per attention block
#define BI   64     // i-rows per iteration
#define SSEG 8      // i-split factor (segments of 1152 rows)
#define SI   72     // Pl row stride (shorts): 144B rows, 16B aligned

typedef __attribute__((ext_vector_type(8))) short short8;
typedef __attribute__((ext_vector_type(4))) float f32x4;

__device__ __forceinline__ unsigned short f2bf(float x) {
    union { float f; unsigned int u; } v; v.f = x;
    return (unsigned short)((v.u + 0x7FFF + ((v.u >> 16) & 1)) >> 16); // RNE
}
__device__ __forceinline__ float bf2f(unsigned short h) {
    union { unsigned int u; float f; } v; v.u = ((unsigned int)h) << 16; return v.f;
}

#if __has_builtin(__builtin_amdgcn_cvt_pk_bf16_f32)
__device__ __forceinline__ unsigned int pack2bf(float a, float b) {
    auto p = __builtin_amdgcn_cvt_pk_bf16_f32(a, b);   // 1 VALU op (gfx950 HW cvt)
    union { decltype(p) v; unsigned int u; } cv; cv.v = p; return cv.u;
}
#else
__device__ __forceinline__ unsigned int pack2bf(float a, float b) {
    return (unsigned)f2bf(a) | ((unsigned)f2bf(b) << 16);
}
#endif

// scores arrive pre-scaled by log2(e)  ->  P = 2^sc = e^s, raw v_exp_f32
#if __has_builtin(__builtin_amdgcn_exp2f)
#define EXP2(x) __builtin_amdgcn_exp2f(x)
#else
#define EXP2(x) __expf((x) * 0.69314718055994531f)
#endif

// ---------------- Kernel 0: w -> bf16 ----------------
__global__ __launch_bounds__(256) void wcvt_kernel(
    const float* __restrict__ w, unsigned short* __restrict__ wbf)
{
    const int i = (blockIdx.x * 256 + threadIdx.x) * 4;  // 320*256 = 81920 elems
    f32x4 v = *(const f32x4*)(w + i);
    *(unsigned int*)(wbf + i)     = pack2bf(v[0], v[1]);
    *(unsigned int*)(wbf + i + 2) = pack2bf(v[2], v[3]);
}

// ---------------- Kernel 1: QKV projection via MFMA (validated R8-R10, ~40 us) ----------------
// qkv[o][n] = sum_c w[o][c]*x[b][c][n].  Block = 16-n-tile; wave wv owns
// o in [80wv, 80wv+80) as 5 o-tiles of 16.  A = wbf rows (contiguous short8),
// B = x columns built in-register from 8 coalesced dword loads + cvt.
// qT is pre-scaled by log2(e) so attn can use raw v_exp_f32.
__global__ __launch_bounds__(256) void qkv_kernel(
    const float* __restrict__ x, const unsigned short* __restrict__ wbf,
    unsigned short* __restrict__ qT, unsigned short* __restrict__ kT,
    unsigned short* __restrict__ vcn)
{
    const int id   = blockIdx.x;      // 1152 = 576 n-tiles x 2 b
    const int b    = id & 1;
    const int n0   = (id >> 1) * 16;
    const int t    = threadIdx.x;
    const int wv   = t >> 6;
    const int lane = t & 63;
    const int l15  = lane & 15;
    const int qd   = lane >> 4;

    const float* xb = x + (size_t)b * CCH * NTOK + n0 + l15;

    f32x4 acc[5];
#pragma unroll
    for (int tt = 0; tt < 5; ++tt) acc[tt] = (f32x4){0.f, 0.f, 0.f, 0.f};

    const unsigned short* wrow = wbf + (size_t)(80 * wv + l15) * CCH + qd * 8;

#pragma unroll
    for (int kk = 0; kk < 8; ++kk) {
        // B-frag: B[k=c=32kk+8qd+e][n=n0+l15]; 8 coalesced dword loads
        float xe[8];
#pragma unroll
        for (int e = 0; e < 8; ++e)
            xe[e] = xb[(size_t)(32 * kk + 8 * qd + e) * NTOK];
        short8 bfr;
#pragma unroll
        for (int e = 0; e < 8; ++e)
            bfr[e] = (short)f2bf(xe[e]);
        // A-frags: A[m=o-local=l15][k=32kk+8qd+e] from wbf row o=80wv+16tt+l15
#pragma unroll
        for (int tt = 0; tt < 5; ++tt) {
            short8 afr = *(const short8*)(wrow + (size_t)(16 * tt) * CCH + 32 * kk);
            acc[tt] = __builtin_amdgcn_mfma_f32_16x16x32_bf16(afr, bfr, acc[tt], 0, 0, 0);
        }
    }

    // store: D[row = o_local = 4qd+r][col = n = n0+l15]; branch uniform per (wv,tt)
    const int n = n0 + l15;
    const float L2E = 1.44269504088896f;
#pragma unroll
    for (int tt = 0; tt < 5; ++tt) {
        const int o0l = 80 * wv + 16 * tt + 4 * qd;   // + r, r=0..3
        if (o0l < 32) {
            unsigned short* d = qT + ((size_t)b * NTOK + n) * DQK + o0l;
            *(unsigned int*)d       = pack2bf(acc[tt][0] * L2E, acc[tt][1] * L2E);
            *(unsigned int*)(d + 2) = pack2bf(acc[tt][2] * L2E, acc[tt][3] * L2E);
        } else if (o0l < 64) {
            unsigned short* d = kT + ((size_t)b * NTOK + n) * DQK + (o0l - 32);
            *(unsigned int*)d       = pack2bf(acc[tt][0], acc[tt][1]);
            *(unsigned int*)(d + 2) = pack2bf(acc[tt][2], acc[tt][3]);
        } else {
            unsigned short* d = vcn + ((size_t)b * CCH + (o0l - 64)) * NTOK + n;
            d[0] = f2bf(acc[tt][0]);
            d[(size_t)NTOK] = f2bf(acc[tt][1]);
            d[(size_t)2 * NTOK] = f2bf(acc[tt][2]);
            d[(size_t)3 * NTOK] = f2bf(acc[tt][3]);
        }
    }
}

// ---------------- Kernel 2: split-i flash attention partials ----------------
// 2304 blocks = 144 (j-block x b) x 16 combos (seg 0..7 x c-half 0..1).
// id = r*16 + combo  ->  xcd = id&7 = combo&7: each XCD holds 2 V-chunks
// (1152 i x 128 c x 2 b x 2 B = 0.59 MB each) -> L2-resident (R7-R10 FETCH
// ~14 MB validates the scheme).  Single Pl buffer (19.4 KB -> LDS allows
// 8 blocks/CU; VGPR 84 -> ~6 waves/SIMD).  9 blocks/CU for latency hiding.
// Opart stored bf16 (halves write traffic; +0.4% partial rounding).
// KEEP __launch_bounds__(256,3): (256,4) caused VGPR 64 + 2 GB spill in R8.
__global__ __launch_bounds__(256, 3) void attn_partial_kernel(
    const unsigned short* __restrict__ qT, const unsigned short* __restrict__ kT,
    const unsigned short* __restrict__ vcn,
    unsigned short* __restrict__ Opart, float* __restrict__ lpart)
{
    __shared__ __align__(16) unsigned short Pl[BJ * SI]; // 18432 B
    __shared__ float lred2[2 * BJ];                      // 1024 B

    const int id    = blockIdx.x;
    const int combo = id & 15;
    const int s     = combo >> 1;      // i-segment 0..7
    const int cb    = combo & 1;       // c-half 0..1
    const int r     = id >> 4;         // 0..143
    const int jb    = r % 72;
    const int b     = r / 72;

    const int t    = threadIdx.x;
    const int wv   = t >> 6;
    const int lane = t & 63;
    const int l15  = lane & 15;
    const int qd   = lane >> 4;
    const int jh   = wv >> 1;          // j-half within block
    const int u    = wv & 1;           // QK: i-subtile bit; PV: c-quarter bit
    const int j0   = jb * BJ;
    const int c0   = cb * 128;
    const int iBeg = s * (NTOK / SSEG);
    const int iEnd = iBeg + (NTOK / SSEG);

    // resident k B-frags: B[k=d=qd*8+e][n=j=64jh+16jt+l15]
    short8 kf[4];
#pragma unroll
    for (int jt = 0; jt < 4; ++jt)
        kf[jt] = *(const short8*)(kT +
            ((size_t)b * NTOK + j0 + 64 * jh + 16 * jt + l15) * DQK + qd * 8);

    f32x4 acc[4][4]; // O[j = j0+64jh+16mt+4qd+r][c = c0+64u+16ct+l15]
#pragma unroll
    for (int mt = 0; mt < 4; ++mt)
#pragma unroll
        for (int ct = 0; ct < 4; ++ct)
            acc[mt][ct] = (f32x4){0.f, 0.f, 0.f, 0.f};
    float lw[4] = {0.f, 0.f, 0.f, 0.f}; // partial l, col j = 64jh+16jt+l15

    const unsigned short* qrow =
        qT + (size_t)b * NTOK * DQK + (size_t)(16 * u + l15) * DQK + qd * 8;
    const unsigned short* vrow =
        vcn + ((size_t)b * CCH + c0 + 64 * u + l15) * NTOK + qd * 8;

    for (int i0 = iBeg; i0 < iEnd; i0 += BI) {
        // A-frags of q rows: af[it] -> i = i0 + 32it + 16u + l15
        short8 af[2];
#pragma unroll
        for (int it = 0; it < 2; ++it)
            af[it] = *(const short8*)(qrow + (size_t)(i0 + 32 * it) * DQK);
        // V B-frags: B[k=i_loc=32kc+qd*8+e][n=c=c0+64u+16ct+l15]
        short8 vf[2][4];
#pragma unroll
        for (int kc = 0; kc < 2; ++kc)
#pragma unroll
            for (int ct = 0; ct < 4; ++ct)
                vf[kc][ct] = *(const short8*)(vrow + (size_t)(16 * ct) * NTOK + i0 + 32 * kc);

        // QK: sc = S[i = i0+32it+16u+4qd+rr][j = j0+64jh+16jt+l15] * log2e
#pragma unroll
        for (int it = 0; it < 2; ++it) {
#pragma unroll
            for (int jt = 0; jt < 4; ++jt) {
                f32x4 sc = __builtin_amdgcn_mfma_f32_16x16x32_bf16(
                    af[it], kf[jt], (f32x4){0.f, 0.f, 0.f, 0.f}, 0, 0, 0);
                float p0 = EXP2(sc[0]);
                float p1 = EXP2(sc[1]);
                float p2 = EXP2(sc[2]);
                float p3 = EXP2(sc[3]);
                lw[jt] += (p0 + p1) + (p2 + p3);
                // Pl[j_loc][i_loc], i_loc = 32it+16u+4qd+{0..3}; 8B-aligned b64
                int base = (64 * jh + 16 * jt + l15) * SI + 32 * it + 16 * u + 4 * qd;
                *(unsigned long long*)(Pl + base) =
                    (unsigned long long)pack2bf(p0, p1) |
                    ((unsigned long long)pack2bf(p2, p3) << 32);
            }
        }
        __syncthreads(); // B1: P visible to all waves

        // PV: A = Pl rows (m=l15 -> j=64jh+16mt+l15, k=32kc+qd*8+e), B = vf
#pragma unroll
        for (int kc = 0; kc < 2; ++kc) {
            short8 pa[4];
#pragma unroll
            for (int mt = 0; mt < 4; ++mt)
                pa[mt] = *(const short8*)(Pl + (64 * jh + 16 * mt + l15) * SI + 32 * kc + qd * 8);
#pragma unroll
            for (int mt = 0; mt < 4; ++mt)
#pragma unroll
                for (int ct = 0; ct < 4; ++ct)
                    acc[mt][ct] = __builtin_amdgcn_mfma_f32_16x16x32_bf16(
                        pa[mt], vf[kc][ct], acc[mt][ct], 0, 0, 0);
        }
        __syncthreads(); // B2: PV reads done before next iteration's P writes
    }

    // l partial: sum over qd (this wave covered i-subsets 32it+16u+[0,16))
#pragma unroll
    for (int jt = 0; jt < 4; ++jt) {
        lw[jt] += __shfl_xor(lw[jt], 16);
        lw[jt] += __shfl_xor(lw[jt], 32);
    }
    if (qd == 0) {
#pragma unroll
        for (int jt = 0; jt < 4; ++jt)
            lred2[u * BJ + 64 * jh + 16 * jt + l15] = lw[jt];
    }
    __syncthreads();
    if (cb == 0 && t < BJ)   // c-half 1 computes identical l; write once
        lpart[(size_t)(s * 2 + b) * NTOK + j0 + t] = lred2[t] + lred2[BJ + t];

    // store raw partial O as bf16 (plain, disjoint, 8B per (mt,ct), coalesced)
#pragma unroll
    for (int mt = 0; mt < 4; ++mt)
#pragma unroll
        for (int ct = 0; ct < 4; ++ct) {
            int c = c0 + 64 * u + 16 * ct + l15;
            int j = j0 + 64 * jh + 16 * mt + 4 * qd;
            unsigned short* p = Opart + ((size_t)(s * 2 + b) * CCH + c) * NTOK + j;
            *(unsigned long long*)p =
                (unsigned long long)pack2bf(acc[mt][ct][0], acc[mt][ct][1]) |
                ((unsigned long long)pack2bf(acc[mt][ct][2], acc[mt][ct][3]) << 32);
        }
}

// ---------------- Kernel 3: reduce partials + normalize + residual ----------------
__global__ __launch_bounds__(256) void reduce_kernel(
    const unsigned short* __restrict__ Opart, const float* __restrict__ lpart,
    const float* __restrict__ x, const float* __restrict__ gamma,
    float* __restrict__ out)
{
    const size_t flat = ((size_t)blockIdx.x * 256 + threadIdx.x) * 4;
    const int j = (int)(flat % NTOK);
    const int b = (int)(flat / ((size_t)CCH * NTOK));
    const size_t inb = flat - (size_t)b * CCH * NTOK;  // c*NTOK + j

    f32x4 o = {0.f, 0.f, 0.f, 0.f};
    f32x4 l = {0.f, 0.f, 0.f, 0.f};
#pragma unroll
    for (int s = 0; s < SSEG; ++s) {
        const size_t plane = (size_t)(s * 2 + b) * CCH * NTOK;
        unsigned long long ov = *(const unsigned long long*)(Opart + plane + inb);
        f32x4 lv = *(const f32x4*)(lpart + (size_t)(s * 2 + b) * NTOK + j);
        o[0] += bf2f((unsigned short)(ov));
        o[1] += bf2f((unsigned short)(ov >> 16));
        o[2] += bf2f((unsigned short)(ov >> 32));
        o[3] += bf2f((unsigned short)(ov >> 48));
        l[0] += lv[0]; l[1] += lv[1]; l[2] += lv[2]; l[3] += lv[3];
    }
    const float g = gamma[0];
    f32x4 xv = *(const f32x4*)(x + flat);
    f32x4 rr;
    rr[0] = g * o[0] / l[0] + xv[0];
    rr[1] = g * o[1] / l[1] + xv[1];
    rr[2] = g * o[2] / l[2] + xv[2];
    rr[3] = g * o[3] / l[3] + xv[3];
    *(f32x4*)(out + flat) = rr;
}

extern "C" void kernel_launch(void* const* d_in, const int* in_sizes, int n_in,
                              void* d_out, int out_size, void* d_ws, size_t ws_size,
                              hipStream_t stream) {
    const float* x     = (const float*)d_in[0];
    const float* w     = (const float*)d_in[1];
    const float* gamma = (const float*)d_in[2];
    float* out = (float*)d_out;

    unsigned short* qT  = (unsigned short*)d_ws;          // 1.18 MB
    unsigned short* kT  = qT + (size_t)2 * NTOK * DQK;    // 1.18 MB
    unsigned short* vcn = kT + (size_t)2 * NTOK * DQK;    // 9.44 MB
    unsigned short* Opart = vcn + (size_t)2 * CCH * NTOK; // 8*2*256*9216 bf16 = 75.5 MB
    float* lpart = (float*)(Opart + (size_t)SSEG * 2 * CCH * NTOK); // 590 KB
    unsigned short* wbf = (unsigned short*)(lpart + (size_t)SSEG * 2 * NTOK); // 164 KB

    wcvt_kernel<<<80, 256, 0, stream>>>(w, wbf);

    qkv_kernel<<<1152, 256, 0, stream>>>(x, wbf, qT, kT, vcn);

    attn_partial_kernel<<<2304, 256, 0, stream>>>(qT, kT, vcn, Opart, lpart);

    reduce_kernel<<<(unsigned)((size_t)2 * CCH * NTOK / 4 / 256), 256, 0, stream>>>(
        Opart, lpart, x, gamma, out);
}